// Round 14
// baseline (109.157 us; speedup 1.0000x reference)
//
#include <hip/hip_runtime.h>
#include <hip/hip_bf16.h>
#include <math.h>

typedef __attribute__((ext_vector_type(4))) float   f32x4;
typedef __attribute__((ext_vector_type(8))) __bf16  bf16x8;
typedef __attribute__((ext_vector_type(8))) unsigned short ushort8;
typedef unsigned short u16;

#define QSCALE 0.1803368801111729f   // 0.125 * log2(e): softmax done in exp2 domain

__device__ __forceinline__ u16 f2b(float f) {
    unsigned u = __builtin_bit_cast(unsigned, f);
    u += 0x7fff + ((u >> 16) & 1);          // RNE
    return (u16)(u >> 16);
}
// async global->LDS, 16B per lane; LDS dest = wave-uniform base + lane*16
__device__ __forceinline__ void gl16(const void* g, void* l) {
    __builtin_amdgcn_global_load_lds((const __attribute__((address_space(1))) void*)g,
                                     (__attribute__((address_space(3))) void*)l, 16, 0, 0);
}
// k-permutation within a 32-elem chunk: dim d stored at pos32(d). Identity:
// pos32(hw_k(j)) = lg*8 + j  ->  MFMA fragment is ONE contiguous 16B read.
__device__ __forceinline__ int pos32(int d) {
    return ((d & 15) >> 2) * 8 + ((d >> 4) & 1) * 4 + (d & 3);
}
// single ds_read_b128 fragment from a 64-col permuted+swizzled LDS tile
__device__ __forceinline__ bf16x8 frag128(const u16* tile, int row, int half, int lg) {
    int gran = (half * 4 + lg) ^ (row & 7);
    return *(const bf16x8*)(tile + row * 64 + gran * 8);
}

// ---------------- fused prep: x/weights f32->bf16 (pos32-k-permuted) + cos/sin table ----------------
__device__ __forceinline__ int permq(int i) {
    int q = i & 7;
    return (i & ~7) | ((q & 3) * 2 + (q >> 2));
}
// blocks [0,4096): x ; [4096,8192): 4 weights ; [8192,8448): csn
__global__ void prep_kernel(const float* __restrict__ x,
                            const float* __restrict__ Wq, const float* __restrict__ Wk,
                            const float* __restrict__ Wv, const float* __restrict__ Wo,
                            const int* __restrict__ pos,
                            u16* __restrict__ xb, u16* __restrict__ wqkv, u16* __restrict__ wob,
                            float2* __restrict__ csn)
{
    int bx = blockIdx.x, tid = threadIdx.x;
    if (bx < 4096) {
        int i = bx * 256 + tid;
        float4 v = ((const float4*)x)[i];
        ((ushort4*)xb)[permq(i)] = make_ushort4(f2b(v.x), f2b(v.y), f2b(v.z), f2b(v.w));
    } else if (bx < 8192) {
        int j = bx - 4096;
        int w = j >> 10;
        int i = (j & 1023) * 256 + tid;
        const float* s = (w == 0) ? Wq : (w == 1) ? Wk : (w == 2) ? Wv : Wo;
        u16* d = (w == 3) ? wob : (wqkv + (size_t)w * 1048576);
        float4 v = ((const float4*)s)[i];
        ((ushort4*)d)[permq(i)] = make_ushort4(f2b(v.x), f2b(v.y), f2b(v.z), f2b(v.w));
    } else {
        int idx = (bx - 8192) * 256 + tid;       // [0, 65536)
        int s = idx >> 5, i = idx & 31;
        float p = (float)pos[s];
        float ang = p * exp2f((float)i * (-13.28771237954945f / 32.f));
        csn[idx] = make_float2(cosf(ang), sinf(ang));
    }
}

// ---- GEMM K-loop: 1024 threads (16 waves, 4M x 4N), BK=64, LDS dbuf, stage-next-then-compute ----
// per-wave output 32x32: acc[2][2]. A,B pos32-k-permuted in global. 1 gl16/thread/operand.
#define GEMM_STAGE(A_, B_, Kd_, kt_, dA_, dB_)                                              \
    {                                                                                       \
        int c = tid;                                                                        \
        int row = c >> 3;                                                                   \
        int col = (((c & 7) ^ (row & 7))) * 8;                                              \
        gl16((A_) + (size_t)(mblk + row) * (Kd_) + (kt_) + col, (dA_) + c * 8);             \
        gl16((B_) + (size_t)(nblk + row) * (Kd_) + (kt_) + col, (dB_) + c * 8);             \
    }

#define GEMM_CORE(A_, B_, Kd_)                                                              \
    GEMM_STAGE(A_, B_, Kd_, 0, lsA, lsB)                                                    \
    for (int it = 0; it < (Kd_) >> 6; ++it) {                                               \
        const int cur = it & 1;                                                             \
        const u16* cA = lsA + cur * 8192;                                                   \
        const u16* cB = lsB + cur * 8192;                                                   \
        __syncthreads();    /* buf[cur] staged; prev reads of buf[cur^1] done */            \
        if (it + 1 < ((Kd_) >> 6)) {                                                        \
            GEMM_STAGE(A_, B_, Kd_, (it + 1) * 64, lsA + (cur ^ 1) * 8192,                  \
                       lsB + (cur ^ 1) * 8192)                                              \
        }                                                                                   \
        bf16x8 af[2][2], bfr[2][2];                                                         \
        _Pragma("unroll")                                                                   \
        for (int mm = 0; mm < 2; ++mm) {                                                    \
            af[mm][0] = frag128(cA, m0 + mm * 16 + l15, 0, lg);                             \
            af[mm][1] = frag128(cA, m0 + mm * 16 + l15, 1, lg);                             \
        }                                                                                   \
        _Pragma("unroll")                                                                   \
        for (int nn = 0; nn < 2; ++nn) {                                                    \
            bfr[nn][0] = frag128(cB, n0 + nn * 16 + l15, 0, lg);                            \
            bfr[nn][1] = frag128(cB, n0 + nn * 16 + l15, 1, lg);                            \
        }                                                                                   \
        _Pragma("unroll")                                                                   \
        for (int mm = 0; mm < 2; ++mm)                                                      \
            _Pragma("unroll")                                                               \
            for (int nn = 0; nn < 2; ++nn) {                                                \
                acc[mm][nn] = __builtin_amdgcn_mfma_f32_16x16x32_bf16(af[mm][0], bfr[nn][0], acc[mm][nn], 0, 0, 0); \
                acc[mm][nn] = __builtin_amdgcn_mfma_f32_16x16x32_bf16(af[mm][1], bfr[nn][1], acc[mm][nn], 0, 0, 0); \
            }                                                                               \
    }

// ---------------- fused QKV GEMM: persistent role-blocks ----------------
// 256 blocks x 1024 threads, 1 block/CU; each block: fixed (mblk, nb), roles Q,K,V sequential.
__global__ __launch_bounds__(1024, 4) void gemm_qkv(
    const u16* __restrict__ A, const u16* __restrict__ Bw, const float2* __restrict__ csn,
    u16* __restrict__ Qh, u16* __restrict__ Kh, u16* __restrict__ Vt)
{
    __shared__ u16 shm[32768];                   // 64 KB: A dbuf [0,16384), B dbuf [16384,32768)
    u16* lsA = shm;
    u16* lsB = shm + 16384;
    const int tid = threadIdx.x;
    const int lane = tid & 63, wv = tid >> 6;    // 16 waves: wr = wv>>2, wc = wv&3
    const int l15 = lane & 15, lg = lane >> 4;
    const int id = blockIdx.x;
    const int xcd = id & 7, slot = id >> 3;      // 32 slots/XCD
    const int nb = (xcd & 1) * 4 + (slot & 3);   // N-col within role (0..7)
    const int by = (xcd >> 1) * 8 + (slot >> 2); // M-row (0..31)
    const int mblk = by * 128;
    const int m0 = (wv >> 2) * 32, n0 = (wv & 3) * 32;

    for (int role = 0; role < 3; ++role) {
        const int nblk = role * 1024 + nb * 128;
        f32x4 acc[2][2];
#pragma unroll
        for (int a = 0; a < 2; ++a)
            for (int b = 0; b < 2; ++b)
                for (int r = 0; r < 4; ++r) acc[a][b][r] = 0.f;

        GEMM_CORE(A, Bw, 1024)

        if (role < 2) {
            // RoPE epilogue: partner value lives in lane^1 (adjacent e)
            u16* dst = role ? Kh : Qh;
            const float scale = role ? 1.f : QSCALE;
#pragma unroll
            for (int mm = 0; mm < 2; ++mm)
#pragma unroll
                for (int nn = 0; nn < 2; ++nn) {
                    int colq = (nblk + n0 + nn * 16 + l15) & 1023;
                    int h = colq >> 6, dd = colq & 63;
                    int outd = (dd & 32) + pos32(dd & 31);
                    int odd = dd & 1, i = dd >> 1;
#pragma unroll
                    for (int r = 0; r < 4; ++r) {
                        int rowg = mblk + m0 + mm * 16 + lg * 4 + r;
                        int b = rowg >> 11, s = rowg & 2047;
                        float2 cs = csn[s * 32 + i];
                        float v = acc[mm][nn][r];
                        float p = __shfl_xor(v, 1);
                        float o = odd ? (p * cs.y + v * cs.x) : (v * cs.x - p * cs.y);
                        dst[((size_t)(b * 16 + h) * 2048 + s) * 64 + outd] = f2b(o * scale);
                    }
                }
            // no barrier needed before next role's stage: buf0's last read completed
            // at the it=15 top barrier; RoPE epilogue touches only globals.
        } else {
            // V transpose epilogue via LDS (128 s-rows x 128 e-cols, stride 132)
            __syncthreads();                     // all waves done reading gemm bufs
#pragma unroll
            for (int mm = 0; mm < 2; ++mm)
#pragma unroll
                for (int nn = 0; nn < 2; ++nn)
#pragma unroll
                    for (int r = 0; r < 4; ++r)
                        shm[(m0 + mm * 16 + lg * 4 + r) * 132 + n0 + nn * 16 + l15] = f2b(acc[mm][nn][r]);
            __syncthreads();
            if (tid < 512) {                     // proven 512-thread gather path
                const int el = tid & 127, hq = tid >> 7; // e-col, s-quarter (32 s each)
                const int colg = nblk - 2048 + el;
                const int h = colg >> 6, dd = colg & 63;
                const int b = mblk >> 11;
                const int sbase = (mblk & 2047) + hq * 32;
                u16 vals[32];
#pragma unroll
                for (int o = 0; o < 32; ++o) {
                    int d = ((o >> 2) & 1) * 16 + (o >> 3) * 4 + (o & 3); // inv pos32 within 32
                    vals[o] = shm[(hq * 32 + d) * 132 + el];
                }
                u16* dst = Vt + ((size_t)(b * 16 + h) * 64 + dd) * 2048 + sbase;
#pragma unroll
                for (int a = 0; a < 4; ++a)
                    *(ushort8*)(dst + a * 8) = *(const ushort8*)(vals + a * 8);
            }
        }
    }
}

// ---------------- out-proj GEMM: C[4096,1024] = Oa * Wo^T -> f32 ----------------
__global__ __launch_bounds__(1024, 4) void gemm_bt(
    const u16* __restrict__ A, const u16* __restrict__ Bw, float* __restrict__ Cf)
{
    __shared__ u16 shm[32768];
    u16* lsA = shm;
    u16* lsB = shm + 16384;
    const int tid = threadIdx.x;
    const int lane = tid & 63, wv = tid >> 6;
    const int l15 = lane & 15, lg = lane >> 4;
    const int id = blockIdx.x;
    const int xcd = id & 7, slot = id >> 3;      // 32 slots/XCD
    const int bx = (xcd & 1) * 4 + (slot & 3);
    const int by = (xcd >> 1) * 8 + (slot >> 2);
    const int mblk = by * 128, nblk = bx * 128;
    const int m0 = (wv >> 2) * 32, n0 = (wv & 3) * 32;

    f32x4 acc[2][2];
#pragma unroll
    for (int a = 0; a < 2; ++a)
        for (int b = 0; b < 2; ++b)
            for (int r = 0; r < 4; ++r) acc[a][b][r] = 0.f;

    GEMM_CORE(A, Bw, 1024)

#pragma unroll
    for (int mm = 0; mm < 2; ++mm)
#pragma unroll
        for (int nn = 0; nn < 2; ++nn)
#pragma unroll
            for (int r = 0; r < 4; ++r) {
                int row = mblk + m0 + mm * 16 + lg * 4 + r;
                int col = nblk + n0 + nn * 16 + l15;
                Cf[(size_t)row * 1024 + col] = acc[mm][nn][r];
            }
}

// ---------------- Flash attention: 8 waves, QBLK=128, KVBLK=128, dbuf, fixed-max softmax ----------------
__device__ __forceinline__ void stage_kv128(const u16* Kp, const u16* Vp, int t,
                                            u16* bK, u16* bV, int tid, int wv) {
#pragma unroll
    for (int r = 0; r < 2; ++r) {
        int c = r * 512 + tid;
        int krow = c >> 3;                       // key-local 0..127
        int kcol = ((c & 7) ^ (krow & 7)) * 8;
        gl16(Kp + (size_t)(t * 128 + krow) * 64 + kcol, bK + (r * 512 + wv * 64) * 8);
        int d = krow & 63, ss = krow >> 6;       // V: rows d, subtile ss
        int vcol = ((c & 7) ^ (d & 7)) * 8;
        gl16(Vp + (size_t)d * 2048 + t * 128 + ss * 64 + vcol, bV + (r * 512 + wv * 64) * 8);
    }
}
__global__ __launch_bounds__(512) void attn_kernel(
    const u16* __restrict__ Qh, const u16* __restrict__ Kh, const u16* __restrict__ Vt,
    u16* __restrict__ Oa)
{
    __shared__ u16 shm[32768];                   // 64 KB
    const int tid = threadIdx.x;
    const int lane = tid & 63, wv = tid >> 6;    // wv 0..7
    const int l15 = lane & 15, lg = lane >> 4;
    const int id = blockIdx.x;
    const int gq = id >> 5;
    const int qt = (id < 256) ? (15 - gq) : (gq - 8);   // heavy+light pairing
    const int bh = id & 31;
    const int b = bh >> 4, h = bh & 15;
    const u16* Qp = Qh + (size_t)bh * 2048 * 64;
    const u16* Kp = Kh + (size_t)bh * 2048 * 64;
    const u16* Vp = Vt + (size_t)bh * 64 * 2048;

    // all-ones A-fragment: row-sum of P via MFMA (denominator)
    const __bf16 one = (__bf16)1.0f;
    const bf16x8 ones = { one, one, one, one, one, one, one, one };

    // stage Q (128x64) into shm[0,8192)
#pragma unroll
    for (int r = 0; r < 2; ++r) {
        int c = r * 512 + tid;
        int row = c >> 3;
        int col = ((c & 7) ^ (row & 7)) * 8;
        gl16(Qp + (size_t)(qt * 128 + row) * 64 + col, shm + (r * 512 + wv * 64) * 8);
    }
    __syncthreads();
    bf16x8 qf[2];                                // wave's 16 q-rows
#pragma unroll
    for (int ds = 0; ds < 2; ++ds)
        qf[ds] = frag128(shm, wv * 16 + l15, ds, lg);
    __syncthreads();                             // everyone done reading Q

    stage_kv128(Kp, Vp, 0, shm, shm + 16384, tid, wv);
    __syncthreads();                             // KV tile 0 ready

    f32x4 accO[4];
#pragma unroll
    for (int dm = 0; dm < 4; ++dm)
        for (int r = 0; r < 4; ++r) accO[dm][r] = 0.f;
    f32x4 accL = { 0.f, 0.f, 0.f, 0.f };         // running sum of P (denominator)
    const int st_b = 2 * qt + (wv >> 2);         // boundary 64-key subtile for this wave
    const int NT = qt + 1;                       // 128-key tiles

    for (int t = 0; t < NT; ++t) {
        const int cur = t & 1;
        if (t + 1 < NT)
            stage_kv128(Kp, Vp, t + 1, shm + (cur ^ 1) * 8192, shm + 16384 + (cur ^ 1) * 8192, tid, wv);
        const u16* Kt = shm + cur * 8192;
        const u16* Vb = shm + 16384 + cur * 8192;
#pragma unroll
        for (int ss = 0; ss < 2; ++ss) {
            const int st = 2 * t + ss;
            if (st <= st_b) {
                f32x4 sa[4];
                __builtin_amdgcn_s_setprio(1);
#pragma unroll
                for (int kb = 0; kb < 4; ++kb) {
                    int krow = ss * 64 + kb * 16 + l15;
                    bf16x8 kf0 = frag128(Kt, krow, 0, lg);
                    bf16x8 kf1 = frag128(Kt, krow, 1, lg);
                    f32x4 s = { 0.f, 0.f, 0.f, 0.f };
                    s = __builtin_amdgcn_mfma_f32_16x16x32_bf16(kf0, qf[0], s, 0, 0, 0);
                    s = __builtin_amdgcn_mfma_f32_16x16x32_bf16(kf1, qf[1], s, 0, 0, 0);
                    sa[kb] = s;
                }
                __builtin_amdgcn_s_setprio(0);
                if (st == st_b) {                // boundary subtile: causal mask
                    int qg = qt * 128 + wv * 16 + l15;
#pragma unroll
                    for (int kb = 0; kb < 4; ++kb)
#pragma unroll
                        for (int r = 0; r < 4; ++r)
                            if (st * 64 + kb * 16 + lg * 4 + r > qg) sa[kb][r] = -1e30f;
                }
                // fixed-max softmax: exp2 directly; denominator normalizes.
#pragma unroll
                for (int kb = 0; kb < 4; ++kb)
#pragma unroll
                    for (int r = 0; r < 4; ++r)
                        sa[kb][r] = exp2f(sa[kb][r]);
                bf16x8 pf[2];
#pragma unroll
                for (int ks = 0; ks < 2; ++ks) {
                    bf16x8 tt;
#pragma unroll
                    for (int j = 0; j < 4; ++j) {
                        tt[j]     = (__bf16)sa[2 * ks][j];
                        tt[4 + j] = (__bf16)sa[2 * ks + 1][j];
                    }
                    pf[ks] = tt;
                }
                __builtin_amdgcn_s_setprio(1);
#pragma unroll
                for (int ks = 0; ks < 2; ++ks)
                    accL = __builtin_amdgcn_mfma_f32_16x16x32_bf16(ones, pf[ks], accL, 0, 0, 0);
#pragma unroll
                for (int dm = 0; dm < 4; ++dm) {
                    int vrow = ss * 64 + dm * 16 + l15;
#pragma unroll
                    for (int ks = 0; ks < 2; ++ks) {
                        bf16x8 vf = frag128(Vb, vrow, ks, lg);
                        accO[dm] = __builtin_amdgcn_mfma_f32_16x16x32_bf16(vf, pf[ks], accO[dm], 0, 0, 0);
                    }
                }
                __builtin_amdgcn_s_setprio(0);
            }
        }
        __syncthreads();                         // next tile staged + this tile's reads done
    }
    float inv = 1.f / accL[0];
    int srow = qt * 128 + wv * 16 + l15;
#pragma unroll
    for (int dm = 0; dm < 4; ++dm) {
        // Oa written pos32-k-permuted (it feeds gemm_bt's A): quad remap within 32-chunk
        int cb = h * 64 + dm * 16 + lg * 4;
        int q = (cb >> 2) & 7;
        int cbp = (cb & ~31) | (((q & 3) * 2 + (q >> 2)) * 4);
        ushort4 o = make_ushort4(f2b(accO[dm][0] * inv), f2b(accO[dm][1] * inv),
                                 f2b(accO[dm][2] * inv), f2b(accO[dm][3] * inv));
        *(ushort4*)&Oa[((size_t)b * 2048 + srow) * 1024 + cbp] = o;
    }
}

extern "C" void kernel_launch(void* const* d_in, const int* in_sizes, int n_in,
                              void* d_out, int out_size, void* d_ws, size_t ws_size,
                              hipStream_t stream) {
    const float* x  = (const float*)d_in[0];
    const int*   pos = (const int*)d_in[1];
    const float* Wq = (const float*)d_in[2];
    const float* Wk = (const float*)d_in[3];
    const float* Wv = (const float*)d_in[4];
    const float* Wo = (const float*)d_in[5];
    float* out = (float*)d_out;
    char* ws = (char*)d_ws;
    const size_t MB = 1024 * 1024;
    u16*    xb   = (u16*)   (ws + 0);        //  8 MB  x bf16, k-permuted
    u16*    wqkv = (u16*)   (ws + 8  * MB);  //  6 MB  [Wq;Wk;Wv], k-permuted
    u16*    wob  = (u16*)   (ws + 14 * MB);  //  2 MB  k-permuted
    float2* csn  = (float2*)(ws + 16 * MB);  //  0.5 MB cos/sin table (2048x32)
    u16*    Qh   = (u16*)   (ws + 24 * MB);  //  8 MB  (b,h,s,d') pre-scaled, d-permuted
    u16*    Kh   = (u16*)   (ws + 32 * MB);  //  8 MB
    u16*    Vt   = (u16*)   (ws + 40 * MB);  //  8 MB  (b,h,d,s') s-permuted
    u16*    Oa   = (u16*)   (ws + 48 * MB);  //  8 MB  attn out, k-permuted

    prep_kernel<<<8448, 256, 0, stream>>>(x, Wq, Wk, Wv, Wo, pos, xb, wqkv, wob, csn);

    gemm_qkv<<<256, 1024, 0, stream>>>(xb, wqkv, csn, Qh, Kh, Vt);

    attn_kernel<<<512, 512, 0, stream>>>(Qh, Kh, Vt, Oa);

    gemm_bt<<<256, 1024, 0, stream>>>(Oa, wob, out);
}

// Round 15
// 89.339 us; speedup vs baseline: 1.2218x; 1.2218x over previous
//
#include <hip/hip_runtime.h>
#include <hip/hip_bf16.h>
#include <math.h>

typedef __attribute__((ext_vector_type(4))) float   f32x4;
typedef __attribute__((ext_vector_type(8))) __bf16  bf16x8;
typedef __attribute__((ext_vector_type(8))) unsigned short ushort8;
typedef unsigned short u16;

#define QSCALE 0.1803368801111729f   // 0.125 * log2(e): softmax done in exp2 domain

__device__ __forceinline__ u16 f2b(float f) {
    unsigned u = __builtin_bit_cast(unsigned, f);
    u += 0x7fff + ((u >> 16) & 1);          // RNE
    return (u16)(u >> 16);
}
// async global->LDS, 16B per lane; LDS dest = wave-uniform base + lane*16
__device__ __forceinline__ void gl16(const void* g, void* l) {
    __builtin_amdgcn_global_load_lds((const __attribute__((address_space(1))) void*)g,
                                     (__attribute__((address_space(3))) void*)l, 16, 0, 0);
}
// k-permutation within a 32-elem chunk: dim d stored at pos32(d). Identity:
// pos32(hw_k(j)) = lg*8 + j  ->  MFMA fragment is ONE contiguous 16B read.
__device__ __forceinline__ int pos32(int d) {
    return ((d & 15) >> 2) * 8 + ((d >> 4) & 1) * 4 + (d & 3);
}
// single ds_read_b128 fragment from a 64-col permuted+swizzled LDS tile
__device__ __forceinline__ bf16x8 frag128(const u16* tile, int row, int half, int lg) {
    int gran = (half * 4 + lg) ^ (row & 7);
    return *(const bf16x8*)(tile + row * 64 + gran * 8);
}

// ---------------- fused prep: x/weights f32->bf16 (pos32-k-permuted) + cos/sin table ----------------
__device__ __forceinline__ int permq(int i) {
    int q = i & 7;
    return (i & ~7) | ((q & 3) * 2 + (q >> 2));
}
// blocks [0,4096): x ; [4096,8192): 4 weights ; [8192,8448): csn
__global__ void prep_kernel(const float* __restrict__ x,
                            const float* __restrict__ Wq, const float* __restrict__ Wk,
                            const float* __restrict__ Wv, const float* __restrict__ Wo,
                            const int* __restrict__ pos,
                            u16* __restrict__ xb, u16* __restrict__ wqkv, u16* __restrict__ wob,
                            float2* __restrict__ csn)
{
    int bx = blockIdx.x, tid = threadIdx.x;
    if (bx < 4096) {
        int i = bx * 256 + tid;
        float4 v = ((const float4*)x)[i];
        ((ushort4*)xb)[permq(i)] = make_ushort4(f2b(v.x), f2b(v.y), f2b(v.z), f2b(v.w));
    } else if (bx < 8192) {
        int j = bx - 4096;
        int w = j >> 10;
        int i = (j & 1023) * 256 + tid;
        const float* s = (w == 0) ? Wq : (w == 1) ? Wk : (w == 2) ? Wv : Wo;
        u16* d = (w == 3) ? wob : (wqkv + (size_t)w * 1048576);
        float4 v = ((const float4*)s)[i];
        ((ushort4*)d)[permq(i)] = make_ushort4(f2b(v.x), f2b(v.y), f2b(v.z), f2b(v.w));
    } else {
        int idx = (bx - 8192) * 256 + tid;       // [0, 65536)
        int s = idx >> 5, i = idx & 31;
        float p = (float)pos[s];
        float ang = p * exp2f((float)i * (-13.28771237954945f / 32.f));
        csn[idx] = make_float2(cosf(ang), sinf(ang));
    }
}

// ---- GEMM K-loop: 512 threads (8 waves, 2M x 4N), BK=64, LDS dbuf, stage-next-then-compute ----
// per-wave output 64x32: acc[4][2]. A,B pos32-k-permuted in global. (round-13 proven core)
#define GEMM_STAGE(A_, B_, Kd_, kt_, dA_, dB_)                                              \
    _Pragma("unroll")                                                                       \
    for (int r = 0; r < 2; ++r) {                                                           \
        int c = r * 512 + tid;                                                              \
        int row = c >> 3;                                                                   \
        int col = (((c & 7) ^ (row & 7))) * 8;                                              \
        gl16((A_) + (size_t)(mblk + row) * (Kd_) + (kt_) + col, (dA_) + c * 8);             \
        gl16((B_) + (size_t)(nblk + row) * (Kd_) + (kt_) + col, (dB_) + c * 8);             \
    }

#define GEMM_CORE(A_, B_, Kd_)                                                              \
    GEMM_STAGE(A_, B_, Kd_, 0, lsA, lsB)                                                    \
    for (int it = 0; it < (Kd_) >> 6; ++it) {                                               \
        const int cur = it & 1;                                                             \
        const u16* cA = lsA + cur * 8192;                                                   \
        const u16* cB = lsB + cur * 8192;                                                   \
        __syncthreads();    /* buf[cur] staged; prev reads of buf[cur^1] done */            \
        if (it + 1 < ((Kd_) >> 6)) {                                                        \
            GEMM_STAGE(A_, B_, Kd_, (it + 1) * 64, lsA + (cur ^ 1) * 8192,                  \
                       lsB + (cur ^ 1) * 8192)                                              \
        }                                                                                   \
        bf16x8 af[4][2], bfr[2][2];                                                         \
        _Pragma("unroll")                                                                   \
        for (int mm = 0; mm < 4; ++mm) {                                                    \
            af[mm][0] = frag128(cA, m0 + mm * 16 + l15, 0, lg);                             \
            af[mm][1] = frag128(cA, m0 + mm * 16 + l15, 1, lg);                             \
        }                                                                                   \
        _Pragma("unroll")                                                                   \
        for (int nn = 0; nn < 2; ++nn) {                                                    \
            bfr[nn][0] = frag128(cB, n0 + nn * 16 + l15, 0, lg);                            \
            bfr[nn][1] = frag128(cB, n0 + nn * 16 + l15, 1, lg);                            \
        }                                                                                   \
        _Pragma("unroll")                                                                   \
        for (int mm = 0; mm < 4; ++mm)                                                      \
            _Pragma("unroll")                                                               \
            for (int nn = 0; nn < 2; ++nn) {                                                \
                acc[mm][nn] = __builtin_amdgcn_mfma_f32_16x16x32_bf16(af[mm][0], bfr[nn][0], acc[mm][nn], 0, 0, 0); \
                acc[mm][nn] = __builtin_amdgcn_mfma_f32_16x16x32_bf16(af[mm][1], bfr[nn][1], acc[mm][nn], 0, 0, 0); \
            }                                                                               \
    }

// ---------------- fused QKV GEMM: CU-balanced 1.5-tile persistent blocks ----------------
// 512 blocks x 512 threads; block id does tile slot (id>>3), plus slot+64 when id<256.
// 512 % 8 == 0 keeps the second tile on the same XCD mapping. Each CU: 3 tiles total.
__global__ __launch_bounds__(512) void gemm_qkv(
    const u16* __restrict__ A, const u16* __restrict__ Bw, const float2* __restrict__ csn,
    u16* __restrict__ Qh, u16* __restrict__ Kh, u16* __restrict__ Vt)
{
    __shared__ u16 shm[32768];                   // 64 KB: A dbuf [0,16384), B dbuf [16384,32768)
    u16* lsA = shm;
    u16* lsB = shm + 16384;
    const int tid = threadIdx.x;
    const int lane = tid & 63, wv = tid >> 6;    // 8 waves: wr = wv>>2, wc = wv&3
    const int l15 = lane & 15, lg = lane >> 4;
    const int id = blockIdx.x;
    const int xcd = id & 7;
    const int slot0 = id >> 3;                   // 0..63
    const int ntiles = (id < 256) ? 2 : 1;
    const int m0 = (wv >> 2) * 64, n0 = (wv & 3) * 32;

    for (int tile = 0; tile < ntiles; ++tile) {
        const int slot = slot0 + tile * 64;      // 0..95 per XCD
        const int bx = (xcd & 1) * 12 + slot % 12;
        const int by = (xcd >> 1) * 8 + slot / 12;
        const int mblk = by * 128, nblk = bx * 128;
        if (tile > 0) __syncthreads();           // prev epilogue's LDS reads done

        f32x4 acc[4][2];
#pragma unroll
        for (int a = 0; a < 4; ++a)
            for (int b = 0; b < 2; ++b)
                for (int r = 0; r < 4; ++r) acc[a][b][r] = 0.f;

        GEMM_CORE(A, Bw, 1024)

        const int role = nblk >> 10;             // 0=Q, 1=K, 2=V
        if (role < 2) {
            u16* dst = role ? Kh : Qh;
            const float scale = role ? 1.f : QSCALE;
#pragma unroll
            for (int mm = 0; mm < 4; ++mm)
#pragma unroll
                for (int nn = 0; nn < 2; ++nn) {
                    int colq = (nblk + n0 + nn * 16 + l15) & 1023;
                    int h = colq >> 6, dd = colq & 63;
                    int outd = (dd & 32) + pos32(dd & 31);
                    int odd = dd & 1, i = dd >> 1;
#pragma unroll
                    for (int r = 0; r < 4; ++r) {
                        int rowg = mblk + m0 + mm * 16 + lg * 4 + r;
                        int b = rowg >> 11, s = rowg & 2047;
                        float2 cs = csn[s * 32 + i];
                        float v = acc[mm][nn][r];
                        float p = __shfl_xor(v, 1);
                        float o = odd ? (p * cs.y + v * cs.x) : (v * cs.x - p * cs.y);
                        dst[((size_t)(b * 16 + h) * 2048 + s) * 64 + outd] = f2b(o * scale);
                    }
                }
        } else {
            // V transpose epilogue via LDS (s-rows 0..127 x e-cols 0..127, stride 132)
            __syncthreads();
#pragma unroll
            for (int mm = 0; mm < 4; ++mm)
#pragma unroll
                for (int nn = 0; nn < 2; ++nn)
#pragma unroll
                    for (int r = 0; r < 4; ++r)
                        shm[(m0 + mm * 16 + lg * 4 + r) * 132 + n0 + nn * 16 + l15] = f2b(acc[mm][nn][r]);
            __syncthreads();
            const int el = tid & 127, hq = tid >> 7; // e-col, s-quarter (32 s each)
            const int colg = nblk - 2048 + el;
            const int h = colg >> 6, dd = colg & 63;
            const int b = mblk >> 11;
            const int sbase = (mblk & 2047) + hq * 32;
            u16 vals[32];
#pragma unroll
            for (int o = 0; o < 32; ++o) {
                int d = ((o >> 2) & 1) * 16 + (o >> 3) * 4 + (o & 3);   // inverse of pos32
                vals[o] = shm[(hq * 32 + d) * 132 + el];
            }
            u16* dst = Vt + ((size_t)(b * 16 + h) * 64 + dd) * 2048 + sbase;
#pragma unroll
            for (int a = 0; a < 4; ++a)
                *(ushort8*)(dst + a * 8) = *(const ushort8*)(vals + a * 8);
        }
    }
}

// ---------------- out-proj GEMM: C[4096,1024] = Oa * Wo^T -> f32 ----------------
__global__ __launch_bounds__(512) void gemm_bt(
    const u16* __restrict__ A, const u16* __restrict__ Bw, float* __restrict__ Cf)
{
    __shared__ u16 shm[32768];
    u16* lsA = shm;
    u16* lsB = shm + 16384;
    const int tid = threadIdx.x;
    const int lane = tid & 63, wv = tid >> 6;
    const int l15 = lane & 15, lg = lane >> 4;
    const int id = blockIdx.x;
    const int xcd = id & 7, slot = id >> 3;      // 32 slots/XCD
    const int bx = (xcd & 1) * 4 + (slot & 3);
    const int by = (xcd >> 1) * 8 + (slot >> 2);
    const int mblk = by * 128, nblk = bx * 128;
    const int m0 = (wv >> 2) * 64, n0 = (wv & 3) * 32;

    f32x4 acc[4][2];
#pragma unroll
    for (int a = 0; a < 4; ++a)
        for (int b = 0; b < 2; ++b)
            for (int r = 0; r < 4; ++r) acc[a][b][r] = 0.f;

    GEMM_CORE(A, Bw, 1024)

#pragma unroll
    for (int mm = 0; mm < 4; ++mm)
#pragma unroll
        for (int nn = 0; nn < 2; ++nn)
#pragma unroll
            for (int r = 0; r < 4; ++r) {
                int row = mblk + m0 + mm * 16 + lg * 4 + r;
                int col = nblk + n0 + nn * 16 + l15;
                Cf[(size_t)row * 1024 + col] = acc[mm][nn][r];
            }
}

// ---------------- Flash attention: 8 waves, QBLK=128, KVBLK=128, dbuf, fixed-max softmax ----------------
__device__ __forceinline__ void stage_kv128(const u16* Kp, const u16* Vp, int t,
                                            u16* bK, u16* bV, int tid, int wv) {
#pragma unroll
    for (int r = 0; r < 2; ++r) {
        int c = r * 512 + tid;
        int krow = c >> 3;                       // key-local 0..127
        int kcol = ((c & 7) ^ (krow & 7)) * 8;
        gl16(Kp + (size_t)(t * 128 + krow) * 64 + kcol, bK + (r * 512 + wv * 64) * 8);
        int d = krow & 63, ss = krow >> 6;       // V: rows d, subtile ss
        int vcol = ((c & 7) ^ (d & 7)) * 8;
        gl16(Vp + (size_t)d * 2048 + t * 128 + ss * 64 + vcol, bV + (r * 512 + wv * 64) * 8);
    }
}
__global__ __launch_bounds__(512) void attn_kernel(
    const u16* __restrict__ Qh, const u16* __restrict__ Kh, const u16* __restrict__ Vt,
    u16* __restrict__ Oa)
{
    __shared__ u16 shm[32768];                   // 64 KB
    const int tid = threadIdx.x;
    const int lane = tid & 63, wv = tid >> 6;    // wv 0..7
    const int l15 = lane & 15, lg = lane >> 4;
    const int id = blockIdx.x;
    const int gq = id >> 5;
    const int qt = (id < 256) ? (15 - gq) : (gq - 8);   // heavy+light pairing
    const int bh = id & 31;
    const int b = bh >> 4, h = bh & 15;
    const u16* Qp = Qh + (size_t)bh * 2048 * 64;
    const u16* Kp = Kh + (size_t)bh * 2048 * 64;
    const u16* Vp = Vt + (size_t)bh * 64 * 2048;

    // all-ones A-fragment: row-sum of P via MFMA (denominator)
    const __bf16 one = (__bf16)1.0f;
    const bf16x8 ones = { one, one, one, one, one, one, one, one };

    // stage Q (128x64) into shm[0,8192)
#pragma unroll
    for (int r = 0; r < 2; ++r) {
        int c = r * 512 + tid;
        int row = c >> 3;
        int col = ((c & 7) ^ (row & 7)) * 8;
        gl16(Qp + (size_t)(qt * 128 + row) * 64 + col, shm + (r * 512 + wv * 64) * 8);
    }
    __syncthreads();
    bf16x8 qf[2];                                // wave's 16 q-rows
#pragma unroll
    for (int ds = 0; ds < 2; ++ds)
        qf[ds] = frag128(shm, wv * 16 + l15, ds, lg);
    __syncthreads();                             // everyone done reading Q

    stage_kv128(Kp, Vp, 0, shm, shm + 16384, tid, wv);
    __syncthreads();                             // KV tile 0 ready

    f32x4 accO[4];
#pragma unroll
    for (int dm = 0; dm < 4; ++dm)
        for (int r = 0; r < 4; ++r) accO[dm][r] = 0.f;
    f32x4 accL = { 0.f, 0.f, 0.f, 0.f };         // running sum of P (denominator)
    const int st_b = 2 * qt + (wv >> 2);         // boundary 64-key subtile for this wave
    const int NT = qt + 1;                       // 128-key tiles

    for (int t = 0; t < NT; ++t) {
        const int cur = t & 1;
        if (t + 1 < NT)
            stage_kv128(Kp, Vp, t + 1, shm + (cur ^ 1) * 8192, shm + 16384 + (cur ^ 1) * 8192, tid, wv);
        const u16* Kt = shm + cur * 8192;
        const u16* Vb = shm + 16384 + cur * 8192;
#pragma unroll
        for (int ss = 0; ss < 2; ++ss) {
            const int st = 2 * t + ss;
            if (st <= st_b) {
                f32x4 sa[4];
                __builtin_amdgcn_s_setprio(1);
#pragma unroll
                for (int kb = 0; kb < 4; ++kb) {
                    int krow = ss * 64 + kb * 16 + l15;
                    bf16x8 kf0 = frag128(Kt, krow, 0, lg);
                    bf16x8 kf1 = frag128(Kt, krow, 1, lg);
                    f32x4 s = { 0.f, 0.f, 0.f, 0.f };
                    s = __builtin_amdgcn_mfma_f32_16x16x32_bf16(kf0, qf[0], s, 0, 0, 0);
                    s = __builtin_amdgcn_mfma_f32_16x16x32_bf16(kf1, qf[1], s, 0, 0, 0);
                    sa[kb] = s;
                }
                __builtin_amdgcn_s_setprio(0);
                if (st == st_b) {                // boundary subtile: causal mask
                    int qg = qt * 128 + wv * 16 + l15;
#pragma unroll
                    for (int kb = 0; kb < 4; ++kb)
#pragma unroll
                        for (int r = 0; r < 4; ++r)
                            if (st * 64 + kb * 16 + lg * 4 + r > qg) sa[kb][r] = -1e30f;
                }
                // fixed-max softmax: exp2 directly; denominator normalizes.
#pragma unroll
                for (int kb = 0; kb < 4; ++kb)
#pragma unroll
                    for (int r = 0; r < 4; ++r)
                        sa[kb][r] = exp2f(sa[kb][r]);
                bf16x8 pf[2];
#pragma unroll
                for (int ks = 0; ks < 2; ++ks) {
                    bf16x8 tt;
#pragma unroll
                    for (int j = 0; j < 4; ++j) {
                        tt[j]     = (__bf16)sa[2 * ks][j];
                        tt[4 + j] = (__bf16)sa[2 * ks + 1][j];
                    }
                    pf[ks] = tt;
                }
                __builtin_amdgcn_s_setprio(1);
#pragma unroll
                for (int ks = 0; ks < 2; ++ks)
                    accL = __builtin_amdgcn_mfma_f32_16x16x32_bf16(ones, pf[ks], accL, 0, 0, 0);
#pragma unroll
                for (int dm = 0; dm < 4; ++dm) {
                    int vrow = ss * 64 + dm * 16 + l15;
#pragma unroll
                    for (int ks = 0; ks < 2; ++ks) {
                        bf16x8 vf = frag128(Vb, vrow, ks, lg);
                        accO[dm] = __builtin_amdgcn_mfma_f32_16x16x32_bf16(vf, pf[ks], accO[dm], 0, 0, 0);
                    }
                }
                __builtin_amdgcn_s_setprio(0);
            }
        }
        __syncthreads();                         // next tile staged + this tile's reads done
    }
    float inv = 1.f / accL[0];
    int srow = qt * 128 + wv * 16 + l15;
#pragma unroll
    for (int dm = 0; dm < 4; ++dm) {
        // Oa written pos32-k-permuted (it feeds gemm_bt's A): quad remap within 32-chunk
        int cb = h * 64 + dm * 16 + lg * 4;
        int q = (cb >> 2) & 7;
        int cbp = (cb & ~31) | (((q & 3) * 2 + (q >> 2)) * 4);
        ushort4 o = make_ushort4(f2b(accO[dm][0] * inv), f2b(accO[dm][1] * inv),
                                 f2b(accO[dm][2] * inv), f2b(accO[dm][3] * inv));
        *(ushort4*)&Oa[((size_t)b * 2048 + srow) * 1024 + cbp] = o;
    }
}

extern "C" void kernel_launch(void* const* d_in, const int* in_sizes, int n_in,
                              void* d_out, int out_size, void* d_ws, size_t ws_size,
                              hipStream_t stream) {
    const float* x  = (const float*)d_in[0];
    const int*   pos = (const int*)d_in[1];
    const float* Wq = (const float*)d_in[2];
    const float* Wk = (const float*)d_in[3];
    const float* Wv = (const float*)d_in[4];
    const float* Wo = (const float*)d_in[5];
    float* out = (float*)d_out;
    char* ws = (char*)d_ws;
    const size_t MB = 1024 * 1024;
    u16*    xb   = (u16*)   (ws + 0);        //  8 MB  x bf16, k-permuted
    u16*    wqkv = (u16*)   (ws + 8  * MB);  //  6 MB  [Wq;Wk;Wv], k-permuted
    u16*    wob  = (u16*)   (ws + 14 * MB);  //  2 MB  k-permuted
    float2* csn  = (float2*)(ws + 16 * MB);  //  0.5 MB cos/sin table (2048x32)
    u16*    Qh   = (u16*)   (ws + 24 * MB);  //  8 MB  (b,h,s,d') pre-scaled, d-permuted
    u16*    Kh   = (u16*)   (ws + 32 * MB);  //  8 MB
    u16*    Vt   = (u16*)   (ws + 40 * MB);  //  8 MB  (b,h,d,s') s-permuted
    u16*    Oa   = (u16*)   (ws + 48 * MB);  //  8 MB  attn out, k-permuted

    prep_kernel<<<8448, 256, 0, stream>>>(x, Wq, Wk, Wv, Wo, pos, xb, wqkv, wob, csn);

    gemm_qkv<<<512, 512, 0, stream>>>(xb, wqkv, csn, Qh, Kh, Vt);

    attn_kernel<<<512, 512, 0, stream>>>(Qh, Kh, Vt, Oa);

    gemm_bt<<<256, 512, 0, stream>>>(Oa, wob, out);
}